// Round 6
// baseline (413.172 us; speedup 1.0000x reference)
//
#include <hip/hip_runtime.h>
#include <math.h>

#define B_    64
#define T_    2048
#define DRNN  1024
#define DEMB  512
#define DATT  128
#define NF    32
#define KS    31
#define PADL  15
#define TT    32   // t's per thread-tile in energy phase
#define CT    64   // t's per block (chunk)
#define NC    (T_/CT)   // 32 chunks per batch row
#define DEMB4 (DEMB/4)

__device__ __forceinline__ float fast_tanh(float x){
    float e2 = __expf(2.0f * x);
    return 1.0f - 2.0f / (e2 + 1.0f);
}

// ---------------------------------------------------------------------------
// K1: pq[b,a] = hidden[b,:] . Wq[a,:]   (blocks 0..63; 512 thr = 8 waves,
//     each wave 16 a's, lanes split K -> coalesced Wq + shuffle reduce)
//     M2[ck*DATT + a] = sum_f Wd[a,f]*conv_w[f,ck]   (block 64, transposed)
// ---------------------------------------------------------------------------
__global__ __launch_bounds__(512) void prep_kernel(
    const float* __restrict__ hidden, const float* __restrict__ Wq,
    const float* __restrict__ Wd, const float* __restrict__ convw,
    float* __restrict__ pq, float* __restrict__ M2)
{
    const int blk = blockIdx.x;
    const int tid = threadIdx.x;
    if (blk < B_) {
        const int b    = blk;
        const int lane = tid & 63;
        const int w    = tid >> 6;           // wave 0..7 -> a in [w*16, w*16+16)
        float4 h[4];
        #pragma unroll
        for (int j = 0; j < 4; ++j)
            h[j] = *(const float4*)(hidden + b*DRNN + lane*4 + j*256);
        for (int ai = 0; ai < 16; ++ai){
            const int a = w*16 + ai;
            const float4* wq4 = (const float4*)(Wq + (size_t)a*DRNN);
            float acc = 0.f;
            #pragma unroll
            for (int j = 0; j < 4; ++j){
                const float4 q = wq4[lane + j*64];   // coalesced
                acc = fmaf(q.x, h[j].x, acc);
                acc = fmaf(q.y, h[j].y, acc);
                acc = fmaf(q.z, h[j].z, acc);
                acc = fmaf(q.w, h[j].w, acc);
            }
            acc += __shfl_xor(acc, 1, 64);  acc += __shfl_xor(acc, 2, 64);
            acc += __shfl_xor(acc, 4, 64);  acc += __shfl_xor(acc, 8, 64);
            acc += __shfl_xor(acc, 16, 64); acc += __shfl_xor(acc, 32, 64);
            if (lane == 0) pq[b*DATT + a] = acc;
        }
    } else {
        const int a = tid & 127;
        const int g = tid >> 7;              // 0..3, each ~16 of 62 cols
        float wd[NF];
        #pragma unroll
        for (int f = 0; f < NF; ++f) wd[f] = Wd[a*NF + f];
        const int cklo = g*16;
        const int ckhi = (g*16 + 16 < 2*KS) ? (g*16 + 16) : 2*KS;
        for (int ck = cklo; ck < ckhi; ++ck){
            float acc = 0.f;
            #pragma unroll
            for (int f = 0; f < NF; ++f) acc = fmaf(wd[f], convw[f*2*KS + ck], acc);
            M2[ck*DATT + a] = acc;           // transposed store (coalesced)
        }
    }
}

// ---------------------------------------------------------------------------
// K2 (fused energy + chunk-softmax + partial context).
// Grid: x = NC, y = B. Block = 256 = 4 waves. __launch_bounds__(256,5):
// the TWO-PASS FIR (channel 0, fence, channel 1 reusing the same 31-tap
// array) cuts the live set from acc[32]+62 taps (~94) to acc[32]+31 (~80),
// letting a 5th block/CU reside (round 5 proved occupancy is THE lever).
// Barriers: 3 -> 2. aw halo is staged per-wave into a private LDS slice
// (wave reads only what it wrote -> FIR starts with no block barrier).
// Phase 2 is computed redundantly by all 4 waves (64-lane shuffle reduce is
// cheaper than idling 3 waves); pval/ballot stay in registers, so the swt
// compaction buffer is gone — phase 3 walks the ballot with ctz + __shfl
// (entry index is wave-uniform). Accumulation order matches round 5 exactly.
// ---------------------------------------------------------------------------
__global__ __launch_bounds__(256, 5) void fused_kernel(
    const float* __restrict__ pm, const float* __restrict__ awcat,
    const float* __restrict__ pq, const float* __restrict__ M2,
    const float* __restrict__ Wv, const int* __restrict__ mask,
    const float* __restrict__ memory,
    float* __restrict__ pbuf, float* __restrict__ pmax,
    float* __restrict__ psum, float* __restrict__ pctx)
{
    const int b    = blockIdx.y;
    const int cx   = blockIdx.x;
    const int t0   = cx * CT;            // block covers [t0, t0+64)
    const int tid  = threadIdx.x;
    const int wvi  = tid >> 6;           // wave 0..3
    const int lane = tid & 63;
    const int s    = tid >> 7;           // t-tile 0/1
    const int a    = tid & 127;
    const int ts   = t0 + TT * s;

    __shared__ float sawW[4][2][64];     // per-wave aw slice [wave][chan][j]
    __shared__ float sred[2][2][TT];     // [tile][a-half][t]
    __shared__ float4 sacc[128];

    // ---- per-wave mask ballot for this wave's 32 t's (pm-skip bitmap) ----
    int mymk = 0;
    if (lane < 32) mymk = (mask[b*T_ + ts + lane] != 0);
    const unsigned mkb = (unsigned)__ballot(mymk);   // wave-uniform scalar

    // ---- pm -> acc, masked t skipped (wave-uniform scalar branch) ----
    const float* pmb = pm + ((size_t)(b*T_ + ts)) * DATT + a;
    float acc[TT];
    #pragma unroll
    for (int t = 0; t < TT; ++t){
        acc[t] = 0.f;
        if (((mkb >> t) & 1u) == 0u) acc[t] = pmb[(size_t)t * DATT];
    }

    // ---- per-wave aw halo staging (own LDS slice; NO block barrier) ----
    {
        const int tt = ts - PADL + lane;             // j = lane, 0..61 used
        const bool ok = (tt >= 0) && (tt < T_) && (lane < 62);
        sawW[wvi][0][lane] = ok ? awcat[(b*2+0)*T_ + tt] : 0.f;
        sawW[wvi][1][lane] = ok ? awcat[(b*2+1)*T_ + tt] : 0.f;
    }

    const float pqa = pq[b*DATT + a];
    const float wvv = Wv[a];
    #pragma unroll
    for (int t = 0; t < TT; ++t) acc[t] += pqa;

    // ---- two-pass register FIR (31 taps live at a time) ----
    float Ma[KS];
    const float* M2a = M2 + a;
    #pragma unroll
    for (int k = 0; k < KS; ++k) Ma[k] = M2a[(size_t)k * DATT];
    #pragma unroll
    for (int j = 0; j < TT + KS - 1; ++j){
        const float av = sawW[wvi][0][j];
        const int tlo = (j - KS + 1) > 0 ? (j - KS + 1) : 0;
        const int thi = (j < TT - 1) ? j : (TT - 1);
        #pragma unroll
        for (int t = tlo; t <= thi; ++t)
            acc[t] = fmaf(Ma[j - t], av, acc[t]);
    }
    asm volatile("" ::: "memory");       // fence: don't hoist ch1 taps above
    #pragma unroll
    for (int k = 0; k < KS; ++k) Ma[k] = M2a[(size_t)(KS + k) * DATT];
    #pragma unroll
    for (int j = 0; j < TT + KS - 1; ++j){
        const float av = sawW[wvi][1][j];
        const int tlo = (j - KS + 1) > 0 ? (j - KS + 1) : 0;
        const int thi = (j < TT - 1) ? j : (TT - 1);
        #pragma unroll
        for (int t = tlo; t <= thi; ++t)
            acc[t] = fmaf(Ma[j - t], av, acc[t]);
    }

    #pragma unroll
    for (int t = 0; t < TT; ++t) acc[t] = wvv * fast_tanh(acc[t]);

    // ---- multi-value butterfly reduce over the wave's 64 lanes ----
    const int half = a >> 6;
    #pragma unroll
    for (int k = 0; k < 16; ++k){
        const bool hi = (lane & 1) != 0;
        float send = hi ? acc[k] : acc[k+16];
        float recv = __shfl_xor(send, 1, 64);
        acc[k] = (hi ? acc[k+16] : acc[k]) + recv;
    }
    #pragma unroll
    for (int k = 0; k < 8; ++k){
        const bool hi = (lane & 2) != 0;
        float send = hi ? acc[k] : acc[k+8];
        float recv = __shfl_xor(send, 2, 64);
        acc[k] = (hi ? acc[k+8] : acc[k]) + recv;
    }
    #pragma unroll
    for (int k = 0; k < 4; ++k){
        const bool hi = (lane & 4) != 0;
        float send = hi ? acc[k] : acc[k+4];
        float recv = __shfl_xor(send, 4, 64);
        acc[k] = (hi ? acc[k+4] : acc[k]) + recv;
    }
    #pragma unroll
    for (int k = 0; k < 2; ++k){
        const bool hi = (lane & 8) != 0;
        float send = hi ? acc[k] : acc[k+2];
        float recv = __shfl_xor(send, 8, 64);
        acc[k] = (hi ? acc[k+2] : acc[k]) + recv;
    }
    {
        const bool hi = (lane & 16) != 0;
        float send = hi ? acc[0] : acc[1];
        float recv = __shfl_xor(send, 16, 64);
        acc[0] = (hi ? acc[1] : acc[0]) + recv;
    }
    acc[0] += __shfl_xor(acc[0], 32, 64);
    // lane -> t: 5-bit reversal of lane&31
    const int trev = ((lane & 1) << 4) | (((lane >> 1) & 1) << 3) |
                     (((lane >> 2) & 1) << 2) | (((lane >> 3) & 1) << 1) |
                     ((lane >> 4) & 1);
    if (lane < 32) sred[s][half][trev] = acc[0];
    __syncthreads();                     // barrier 1 of 2

    // ---- Phase 2: softmax partials, redundantly on ALL 4 waves ----
    const int tme = t0 + lane;
    float e = sred[lane>>5][0][lane&31] + sred[lane>>5][1][lane&31];
    const int mk2 = (mask[b*T_ + tme] != 0);
    float mval = mk2 ? -1e30f : e;
    #pragma unroll
    for (int off = 1; off < 64; off <<= 1) mval = fmaxf(mval, __shfl_xor(mval, off, 64));
    const float pval = mk2 ? 0.f : __expf(e - mval);
    float sv = pval;
    #pragma unroll
    for (int off = 1; off < 64; off <<= 1) sv += __shfl_xor(sv, off, 64);
    const unsigned long long bal = __ballot(pval != 0.f);
    const int n = (int)__popcll(bal);
    if (wvi == 0){
        pbuf[b*T_ + tme] = pval;
        if (lane == 0){
            pmax[b*NC + cx] = mval;
            psum[b*NC + cx] = sv;
        }
    }

    // ---- Phase 3: context over ballot-compacted rows (no barrier needed:
    //      pval/bal are wave-local; entry index is wave-uniform) ----
    const int col = tid & 127;   // float4 column (0..127)
    const int row = tid >> 7;    // wave-uniform
    float4 a4 = make_float4(0.f, 0.f, 0.f, 0.f);
    const float4* mem4 = (const float4*)memory + ((size_t)(b*T_ + t0))*DEMB4 + col;

    unsigned long long mbits = bal;
    int i = 0;
    for (; i + 8 <= n; i += 8){
        int tb[8];
        #pragma unroll
        for (int u = 0; u < 8; ++u){
            tb[u] = (int)__builtin_ctzll(mbits);
            mbits &= mbits - 1ull;
        }
        const int i0 = tb[row+0], i1 = tb[row+2], i2 = tb[row+4], i3 = tb[row+6];
        const float p0 = __shfl(pval, i0, 64);
        const float p1 = __shfl(pval, i1, 64);
        const float p2 = __shfl(pval, i2, 64);
        const float p3 = __shfl(pval, i3, 64);
        const float4 m0 = mem4[(size_t)i0 * DEMB4];
        const float4 m1 = mem4[(size_t)i1 * DEMB4];
        const float4 m2 = mem4[(size_t)i2 * DEMB4];
        const float4 m3 = mem4[(size_t)i3 * DEMB4];
        a4.x = fmaf(p0, m0.x, a4.x); a4.y = fmaf(p0, m0.y, a4.y);
        a4.z = fmaf(p0, m0.z, a4.z); a4.w = fmaf(p0, m0.w, a4.w);
        a4.x = fmaf(p1, m1.x, a4.x); a4.y = fmaf(p1, m1.y, a4.y);
        a4.z = fmaf(p1, m1.z, a4.z); a4.w = fmaf(p1, m1.w, a4.w);
        a4.x = fmaf(p2, m2.x, a4.x); a4.y = fmaf(p2, m2.y, a4.y);
        a4.z = fmaf(p2, m2.z, a4.z); a4.w = fmaf(p2, m2.w, a4.w);
        a4.x = fmaf(p3, m3.x, a4.x); a4.y = fmaf(p3, m3.y, a4.y);
        a4.z = fmaf(p3, m3.z, a4.z); a4.w = fmaf(p3, m3.w, a4.w);
    }
    for (; i < n; ++i){
        const int tb = (int)__builtin_ctzll(mbits);
        mbits &= mbits - 1ull;
        if ((i & 1) == row){
            const float p = __shfl(pval, tb, 64);
            const float4 m = mem4[(size_t)tb * DEMB4];
            a4.x = fmaf(p, m.x, a4.x); a4.y = fmaf(p, m.y, a4.y);
            a4.z = fmaf(p, m.z, a4.z); a4.w = fmaf(p, m.w, a4.w);
        }
    }

    if (row == 1) sacc[col] = a4;
    __syncthreads();                     // barrier 2 of 2
    if (row == 0){
        const float4 o = sacc[col];
        float4* dst = (float4*)(pctx + ((size_t)(b*NC + cx))*DEMB) + col;
        *dst = make_float4(a4.x + o.x, a4.y + o.y, a4.z + o.z, a4.w + o.w);
    }
}

// ---------------------------------------------------------------------------
// K3 (finalize). Grid (8, B): every block recomputes the per-b scales (cheap,
// 64 floats from L2); block g==0 does ctx (branch-free batched loads);
// all blocks write their 256-t slice of wout.
// ---------------------------------------------------------------------------
__global__ __launch_bounds__(256) void finalize_kernel(
    const float* __restrict__ pbuf, const float* __restrict__ pmax,
    const float* __restrict__ psum, const float* __restrict__ pctx,
    float* __restrict__ ctx, float* __restrict__ wout)
{
    const int b   = blockIdx.y;
    const int g   = blockIdx.x;    // 0..7
    const int tid = threadIdx.x;
    __shared__ float sscale[NC];

    if (tid < 64){
        float mv = (tid < NC) ? pmax[b*NC + tid] : -1e30f;
        float sv = (tid < NC) ? psum[b*NC + tid] : 0.f;
        float gm = mv;
        #pragma unroll
        for (int off = 1; off < 64; off <<= 1) gm = fmaxf(gm, __shfl_xor(gm, off, 64));
        float z = sv * __expf(mv - gm);
        #pragma unroll
        for (int off = 1; off < 64; off <<= 1) z += __shfl_xor(z, off, 64);
        if (tid < NC) sscale[tid] = __expf(mv - gm) / z;
    }
    __syncthreads();

    if (g == 0){
        // ctx: 256 threads x float2 = 512 d's; loads batched (no branch)
        float2 a2 = make_float2(0.f, 0.f);
        const float2* pc2 = (const float2*)(pctx + (size_t)b*NC*DEMB) + tid;
        #pragma unroll
        for (int c = 0; c < NC; ++c){
            const float sc = sscale[c];
            const float2 v = pc2[(size_t)c * (DEMB/2)];
            a2.x = fmaf(sc, v.x, a2.x);
            a2.y = fmaf(sc, v.y, a2.y);
        }
        ((float2*)(ctx + b*DEMB))[tid] = a2;
    }

    // weights: this block's 256-t slice
    const int t = g*256 + tid;
    wout[b*T_ + t] = pbuf[b*T_ + t] * sscale[t >> 6];
}

// ---------------------------------------------------------------------------
extern "C" void kernel_launch(void* const* d_in, const int* in_sizes, int n_in,
                              void* d_out, int out_size, void* d_ws, size_t ws_size,
                              hipStream_t stream)
{
    const float* hidden = (const float*)d_in[0];   // (B, D_RNN)
    const float* memory = (const float*)d_in[1];   // (B, T, D_EMB)
    const float* pm     = (const float*)d_in[2];   // (B, T, D_ATT)
    const float* awcat  = (const float*)d_in[3];   // (B, 2, T)
    const int*   mask   = (const int*)d_in[4];     // (B, T)
    const float* Wq     = (const float*)d_in[5];   // (D_ATT, D_RNN)
    const float* Wv     = (const float*)d_in[6];   // (1, D_ATT)
    const float* convw  = (const float*)d_in[7];   // (NF, 2, KS)
    const float* Wd     = (const float*)d_in[8];   // (D_ATT, NF)

    float* out  = (float*)d_out;
    float* ctx  = out;               // (B, D_EMB)
    float* wout = out + B_*DEMB;     // (B, T)

    float* pq    = (float*)d_ws;             // 8192
    float* M2    = pq   + B_*DATT;           // 8192 (62*128 used)
    float* pbuf  = M2   + 8192;              // B*T = 131072
    float* pmax  = pbuf + B_*T_;             // B*NC = 2048
    float* psum  = pmax + B_*NC;             // 2048
    float* pctx  = psum + B_*NC;             // B*NC*DEMB = 4 MB

    prep_kernel<<<dim3(B_ + 1), 512, 0, stream>>>(hidden, Wq, Wd, convw, pq, M2);
    fused_kernel<<<dim3(NC, B_), 256, 0, stream>>>(pm, awcat, pq, M2, Wv, mask,
                                                   memory, pbuf, pmax, psum, pctx);
    finalize_kernel<<<dim3(8, B_), 256, 0, stream>>>(pbuf, pmax, psum, pctx, ctx, wout);
}

// Round 7
// 407.866 us; speedup vs baseline: 1.0130x; 1.0130x over previous
//
#include <hip/hip_runtime.h>
#include <math.h>

#define B_    64
#define T_    2048
#define DRNN  1024
#define DEMB  512
#define DATT  128
#define NF    32
#define KS    31
#define PADL  15
#define TT    32   // t's per thread-tile in energy phase
#define CT    64   // t's per block (chunk)
#define NC    (T_/CT)   // 32 chunks per batch row

__device__ __forceinline__ float fast_tanh(float x){
    float e2 = __expf(2.0f * x);
    return 1.0f - 2.0f / (e2 + 1.0f);
}

// ---------------------------------------------------------------------------
// K1: pq[b,a] = hidden[b,:] . Wq[a,:]   (blocks 0..63; 512 thr = 8 waves,
//     each wave 16 a's, lanes split K -> coalesced Wq + shuffle reduce)
//     M2[ck*DATT + a] = sum_f Wd[a,f]*conv_w[f,ck]   (block 64, transposed)
// ---------------------------------------------------------------------------
__global__ __launch_bounds__(512) void prep_kernel(
    const float* __restrict__ hidden, const float* __restrict__ Wq,
    const float* __restrict__ Wd, const float* __restrict__ convw,
    float* __restrict__ pq, float* __restrict__ M2)
{
    const int blk = blockIdx.x;
    const int tid = threadIdx.x;
    if (blk < B_) {
        const int b    = blk;
        const int lane = tid & 63;
        const int w    = tid >> 6;           // wave 0..7 -> a in [w*16, w*16+16)
        float4 h[4];
        #pragma unroll
        for (int j = 0; j < 4; ++j)
            h[j] = *(const float4*)(hidden + b*DRNN + lane*4 + j*256);
        for (int ai = 0; ai < 16; ++ai){
            const int a = w*16 + ai;
            const float4* wq4 = (const float4*)(Wq + (size_t)a*DRNN);
            float acc = 0.f;
            #pragma unroll
            for (int j = 0; j < 4; ++j){
                const float4 q = wq4[lane + j*64];   // coalesced
                acc = fmaf(q.x, h[j].x, acc);
                acc = fmaf(q.y, h[j].y, acc);
                acc = fmaf(q.z, h[j].z, acc);
                acc = fmaf(q.w, h[j].w, acc);
            }
            acc += __shfl_xor(acc, 1, 64);  acc += __shfl_xor(acc, 2, 64);
            acc += __shfl_xor(acc, 4, 64);  acc += __shfl_xor(acc, 8, 64);
            acc += __shfl_xor(acc, 16, 64); acc += __shfl_xor(acc, 32, 64);
            if (lane == 0) pq[b*DATT + a] = acc;
        }
    } else {
        const int a = tid & 127;
        const int g = tid >> 7;              // 0..3, each ~16 of 62 cols
        float wd[NF];
        #pragma unroll
        for (int f = 0; f < NF; ++f) wd[f] = Wd[a*NF + f];
        const int cklo = g*16;
        const int ckhi = (g*16 + 16 < 2*KS) ? (g*16 + 16) : 2*KS;
        for (int ck = cklo; ck < ckhi; ++ck){
            float acc = 0.f;
            #pragma unroll
            for (int f = 0; f < NF; ++f) acc = fmaf(wd[f], convw[f*2*KS + ck], acc);
            M2[ck*DATT + a] = acc;           // transposed store (coalesced)
        }
    }
}

// ---------------------------------------------------------------------------
// K2 (fused energy + chunk-softmax + partial context).
// EXACT round-5 winner (404.97 us) with ONE change: phase-3 main loop is
// 8-deep (8 loads in flight/thread, was 4). At 4 blocks/CU the phase-3
// stream was ~1 KB in flight per CU vs ~12 KB needed -> latency-bound;
// doubling depth doubles bytes in flight. FMA order unchanged (ascending i)
// -> bit-identical output. Round-6's two-pass FIR/(256,5)/ctz rework is
// fully reverted (regressed +8 us, suspected spills near the 102-reg cap).
// ---------------------------------------------------------------------------
__global__ __launch_bounds__(256, 4) void fused_kernel(
    const float* __restrict__ pm, const float* __restrict__ awcat,
    const float* __restrict__ pq, const float* __restrict__ M2,
    const float* __restrict__ Wv, const int* __restrict__ mask,
    const float* __restrict__ memory,
    float* __restrict__ pbuf, float* __restrict__ pmax,
    float* __restrict__ psum, float* __restrict__ pctx)
{
    const int b   = blockIdx.y;
    const int cx  = blockIdx.x;
    const int t0  = cx * CT;             // block covers [t0, t0+64)
    const int tid = threadIdx.x;
    const int s   = tid >> 7;            // tile 0/1
    const int a   = tid & 127;
    const int ts  = t0 + TT * s;
    const int lane = tid & 63;

    __shared__ float saw0[96], saw1[96];     // aw[c, t0-15 .. t0+78]
    __shared__ float sred[2][2][TT];         // [tile][a-half][t]
    __shared__ float2 swt[CT];               // compacted (p, t-as-bits)
    __shared__ int   scount;                 // number of compacted rows
    __shared__ float4 sacc[128];
    __shared__ unsigned int smkbits[2];      // mask bitmap for phase 2

    // ---- per-wave mask ballot: bitmap for THIS wave's 32 t's, as SGPR ----
    int mymk = 0;
    if (lane < 32) mymk = (mask[b*T_ + ts + lane] != 0);
    const unsigned long long bal0 = __ballot(mymk);
    const unsigned mkb = (unsigned)bal0;     // wave-uniform scalar

    // ---- front-loaded globals: pm -> acc (masked t skipped), taps, pq, wv ----
    const float pqa = pq[b*DATT + a];
    const float wv  = Wv[a];
    const float* pmb = pm + ((size_t)(b*T_ + ts)) * DATT + a;
    float acc[TT];
    #pragma unroll
    for (int t = 0; t < TT; ++t){
        acc[t] = 0.f;
        if (((mkb >> t) & 1u) == 0u) acc[t] = pmb[(size_t)t * DATT];
    }
    float Ma0[KS], Ma1[KS];
    const float* M2a = M2 + a;
    #pragma unroll
    for (int k = 0; k < KS; ++k){
        Ma0[k] = M2a[(size_t)k * DATT];
        Ma1[k] = M2a[(size_t)(KS + k) * DATT];
    }

    // ---- staging: aw halo + phase-2 mask bitmap ----
    for (int i = tid; i < 94; i += 256){
        int tt = t0 - PADL + i;
        bool ok = (tt >= 0) && (tt < T_);
        saw0[i] = ok ? awcat[(b*2+0)*T_ + tt] : 0.f;
        saw1[i] = ok ? awcat[(b*2+1)*T_ + tt] : 0.f;
    }
    if (tid < 64){                            // wave 0 exactly
        const int mk = mask[b*T_ + t0 + tid] != 0;
        const unsigned long long bal = __ballot(mk);
        if (tid == 0){
            smkbits[0] = (unsigned)bal;
            smkbits[1] = (unsigned)(bal >> 32);
        }
    }
    __syncthreads();

    // ---- Phase 1: FIR ----
    #pragma unroll
    for (int t = 0; t < TT; ++t) acc[t] += pqa;

    #pragma unroll
    for (int j = 0; j < TT + KS - 1; ++j){
        const float av0 = saw0[j + TT*s];
        const float av1 = saw1[j + TT*s];
        const int tlo = (j - KS + 1) > 0 ? (j - KS + 1) : 0;
        const int thi = (j < TT - 1) ? j : (TT - 1);
        #pragma unroll
        for (int t = tlo; t <= thi; ++t){
            acc[t] = fmaf(Ma0[j - t], av0, acc[t]);
            acc[t] = fmaf(Ma1[j - t], av1, acc[t]);
        }
    }

    #pragma unroll
    for (int t = 0; t < TT; ++t){
        acc[t] = wv * fast_tanh(acc[t]);
    }

    // ---- multi-value butterfly reduce over the wave's 64 lanes ----
    const int half = a >> 6;
    #pragma unroll
    for (int k = 0; k < 16; ++k){
        const bool hi = (lane & 1) != 0;
        float send = hi ? acc[k] : acc[k+16];
        float recv = __shfl_xor(send, 1, 64);
        acc[k] = (hi ? acc[k+16] : acc[k]) + recv;
    }
    #pragma unroll
    for (int k = 0; k < 8; ++k){
        const bool hi = (lane & 2) != 0;
        float send = hi ? acc[k] : acc[k+8];
        float recv = __shfl_xor(send, 2, 64);
        acc[k] = (hi ? acc[k+8] : acc[k]) + recv;
    }
    #pragma unroll
    for (int k = 0; k < 4; ++k){
        const bool hi = (lane & 4) != 0;
        float send = hi ? acc[k] : acc[k+4];
        float recv = __shfl_xor(send, 4, 64);
        acc[k] = (hi ? acc[k+4] : acc[k]) + recv;
    }
    #pragma unroll
    for (int k = 0; k < 2; ++k){
        const bool hi = (lane & 8) != 0;
        float send = hi ? acc[k] : acc[k+2];
        float recv = __shfl_xor(send, 8, 64);
        acc[k] = (hi ? acc[k+2] : acc[k]) + recv;
    }
    {
        const bool hi = (lane & 16) != 0;
        float send = hi ? acc[0] : acc[1];
        float recv = __shfl_xor(send, 16, 64);
        acc[0] = (hi ? acc[1] : acc[0]) + recv;
    }
    acc[0] += __shfl_xor(acc[0], 32, 64);
    // lane -> t: 5-bit reversal of lane&31
    const int trev = ((lane & 1) << 4) | (((lane >> 1) & 1) << 3) |
                     (((lane >> 2) & 1) << 2) | (((lane >> 3) & 1) << 1) |
                     ((lane >> 4) & 1);
    if (lane < 32) sred[s][half][trev] = acc[0];
    __syncthreads();

    // ---- Phase 2: chunk softmax partials + ballot-compaction (1 wave) ----
    if (tid < 64){
        const int t = t0 + tid;
        float e = sred[tid>>5][0][tid&31] + sred[tid>>5][1][tid&31];
        const int mk = (smkbits[tid>>5] >> (tid&31)) & 1u;
        float mval = mk ? -1e30f : e;
        #pragma unroll
        for (int off = 1; off < 64; off <<= 1) mval = fmaxf(mval, __shfl_xor(mval, off, 64));
        const float pval = mk ? 0.f : __expf(e - mval);
        float sv = pval;
        #pragma unroll
        for (int off = 1; off < 64; off <<= 1) sv += __shfl_xor(sv, off, 64);
        pbuf[b*T_ + t] = pval;
        const unsigned long long bal = __ballot(pval != 0.f);
        if (pval != 0.f){
            const int pfx = (int)__popcll(bal & ((1ull << tid) - 1ull));
            swt[pfx] = make_float2(pval, __int_as_float(tid));
        }
        if (tid == 0){
            scount = (int)__popcll(bal);
            pmax[b*NC + cx] = mval;
            psum[b*NC + cx] = sv;
        }
    }
    __syncthreads();

    // ---- Phase 3: partial context over compacted rows, branch-free,
    //      8 loads in flight per thread ----
    const int n   = scount;
    const int col = tid & 127;   // float4 column (DEMB/4 = 128)
    const int row = tid >> 7;    // 2 entries in flight
    float4 a4 = make_float4(0.f, 0.f, 0.f, 0.f);
    const float4* mem4 = (const float4*)memory + ((size_t)(b*T_ + t0))*(DEMB/4) + col;

    int i = row;
    for (; i + 14 < n; i += 16){             // 8 loads in flight
        float2 e[8];
        #pragma unroll
        for (int u = 0; u < 8; ++u) e[u] = swt[i + 2*u];
        float4 m[8];
        #pragma unroll
        for (int u = 0; u < 8; ++u)
            m[u] = mem4[(size_t)__float_as_int(e[u].y) * (DEMB/4)];
        #pragma unroll
        for (int u = 0; u < 8; ++u){
            a4.x = fmaf(e[u].x, m[u].x, a4.x);
            a4.y = fmaf(e[u].x, m[u].y, a4.y);
            a4.z = fmaf(e[u].x, m[u].z, a4.z);
            a4.w = fmaf(e[u].x, m[u].w, a4.w);
        }
    }
    for (; i + 6 < n; i += 8){               // 4 loads in flight
        const float2 e0 = swt[i];
        const float2 e1 = swt[i+2];
        const float2 e2 = swt[i+4];
        const float2 e3 = swt[i+6];
        const float4 m0 = mem4[(size_t)__float_as_int(e0.y) * (DEMB/4)];
        const float4 m1 = mem4[(size_t)__float_as_int(e1.y) * (DEMB/4)];
        const float4 m2 = mem4[(size_t)__float_as_int(e2.y) * (DEMB/4)];
        const float4 m3 = mem4[(size_t)__float_as_int(e3.y) * (DEMB/4)];
        a4.x = fmaf(e0.x, m0.x, a4.x); a4.y = fmaf(e0.x, m0.y, a4.y);
        a4.z = fmaf(e0.x, m0.z, a4.z); a4.w = fmaf(e0.x, m0.w, a4.w);
        a4.x = fmaf(e1.x, m1.x, a4.x); a4.y = fmaf(e1.x, m1.y, a4.y);
        a4.z = fmaf(e1.x, m1.z, a4.z); a4.w = fmaf(e1.x, m1.w, a4.w);
        a4.x = fmaf(e2.x, m2.x, a4.x); a4.y = fmaf(e2.x, m2.y, a4.y);
        a4.z = fmaf(e2.x, m2.z, a4.z); a4.w = fmaf(e2.x, m2.w, a4.w);
        a4.x = fmaf(e3.x, m3.x, a4.x); a4.y = fmaf(e3.x, m3.y, a4.y);
        a4.z = fmaf(e3.x, m3.z, a4.z); a4.w = fmaf(e3.x, m3.w, a4.w);
    }
    for (; i < n; i += 2){
        const float2 e = swt[i];
        const float4 m = mem4[(size_t)__float_as_int(e.y) * (DEMB/4)];
        a4.x = fmaf(e.x, m.x, a4.x); a4.y = fmaf(e.x, m.y, a4.y);
        a4.z = fmaf(e.x, m.z, a4.z); a4.w = fmaf(e.x, m.w, a4.w);
    }

    if (row == 1) sacc[col] = a4;
    __syncthreads();
    if (row == 0){
        const float4 o = sacc[col];
        float4* dst = (float4*)(pctx + ((size_t)(b*NC + cx))*DEMB) + col;
        *dst = make_float4(a4.x + o.x, a4.y + o.y, a4.z + o.z, a4.w + o.w);
    }
}

// ---------------------------------------------------------------------------
// K3 (finalize). Grid (8, B): every block recomputes the per-b scales (cheap,
// 64 floats from L2); block g==0 does ctx (branch-free batched loads);
// all blocks write their 256-t slice of wout.
// ---------------------------------------------------------------------------
__global__ __launch_bounds__(256) void finalize_kernel(
    const float* __restrict__ pbuf, const float* __restrict__ pmax,
    const float* __restrict__ psum, const float* __restrict__ pctx,
    float* __restrict__ ctx, float* __restrict__ wout)
{
    const int b   = blockIdx.y;
    const int g   = blockIdx.x;    // 0..7
    const int tid = threadIdx.x;
    __shared__ float sscale[NC];

    if (tid < 64){
        float mv = (tid < NC) ? pmax[b*NC + tid] : -1e30f;
        float sv = (tid < NC) ? psum[b*NC + tid] : 0.f;
        float gm = mv;
        #pragma unroll
        for (int off = 1; off < 64; off <<= 1) gm = fmaxf(gm, __shfl_xor(gm, off, 64));
        float z = sv * __expf(mv - gm);
        #pragma unroll
        for (int off = 1; off < 64; off <<= 1) z += __shfl_xor(z, off, 64);
        if (tid < NC) sscale[tid] = __expf(mv - gm) / z;
    }
    __syncthreads();

    if (g == 0){
        // ctx: 256 threads x float2 = 512 d's; loads batched (no branch)
        float2 a2 = make_float2(0.f, 0.f);
        const float2* pc2 = (const float2*)(pctx + (size_t)b*NC*DEMB) + tid;
        #pragma unroll
        for (int c = 0; c < NC; ++c){
            const float sc = sscale[c];
            const float2 v = pc2[(size_t)c * (DEMB/2)];
            a2.x = fmaf(sc, v.x, a2.x);
            a2.y = fmaf(sc, v.y, a2.y);
        }
        ((float2*)(ctx + b*DEMB))[tid] = a2;
    }

    // weights: this block's 256-t slice
    const int t = g*256 + tid;
    wout[b*T_ + t] = pbuf[b*T_ + t] * sscale[t >> 6];
}

// ---------------------------------------------------------------------------
extern "C" void kernel_launch(void* const* d_in, const int* in_sizes, int n_in,
                              void* d_out, int out_size, void* d_ws, size_t ws_size,
                              hipStream_t stream)
{
    const float* hidden = (const float*)d_in[0];   // (B, D_RNN)
    const float* memory = (const float*)d_in[1];   // (B, T, D_EMB)
    const float* pm     = (const float*)d_in[2];   // (B, T, D_ATT)
    const float* awcat  = (const float*)d_in[3];   // (B, 2, T)
    const int*   mask   = (const int*)d_in[4];     // (B, T)
    const float* Wq     = (const float*)d_in[5];   // (D_ATT, D_RNN)
    const float* Wv     = (const float*)d_in[6];   // (1, D_ATT)
    const float* convw  = (const float*)d_in[7];   // (NF, 2, KS)
    const float* Wd     = (const float*)d_in[8];   // (D_ATT, NF)

    float* out  = (float*)d_out;
    float* ctx  = out;               // (B, D_EMB)
    float* wout = out + B_*DEMB;     // (B, T)

    float* pq    = (float*)d_ws;             // 8192
    float* M2    = pq   + B_*DATT;           // 8192 (62*128 used)
    float* pbuf  = M2   + 8192;              // B*T = 131072
    float* pmax  = pbuf + B_*T_;             // B*NC = 2048
    float* psum  = pmax + B_*NC;             // 2048
    float* pctx  = psum + B_*NC;             // B*NC*DEMB = 4 MB

    prep_kernel<<<dim3(B_ + 1), 512, 0, stream>>>(hidden, Wq, Wd, convw, pq, M2);
    fused_kernel<<<dim3(NC, B_), 256, 0, stream>>>(pm, awcat, pq, M2, Wv, mask,
                                                   memory, pbuf, pmax, psum, pctx);
    finalize_kernel<<<dim3(8, B_), 256, 0, stream>>>(pbuf, pmax, psum, pctx, ctx, wout);
}